// Round 15
// baseline (984.047 us; speedup 1.0000x reference)
//
#include <hip/hip_runtime.h>
#include <math.h>

// B=32, S=2048, D=512, R=4, H=32. Tokens = 65536. Tile = 64 tokens.
#define NTOK 65536
#define TOK 64
#define NTILE 1024

typedef float v2f __attribute__((ext_vector_type(2)));

// Cross-half sum via the gfx950 permlane32_swap BUILTIN (SSA-safe; never the
// inline-asm "+v","+v" form — R4: allocator coalesces identical tied operands
// -> self-swap). r0+r1 == x + shfl_xor(x,32) bit-exactly (fp add commutes).
__device__ __forceinline__ float xhalf_sum(float a) {
    unsigned ai = __builtin_bit_cast(unsigned, a);
    auto r = __builtin_amdgcn_permlane32_swap(ai, ai, false, false);
    return __builtin_bit_cast(float, (unsigned)r[0]) +
           __builtin_bit_cast(float, (unsigned)r[1]);
}

// ---------------------------------------------------------------------------
// Kernel 1: router (UNCHANGED from the passing R5/R10 kernel).
// ---------------------------------------------------------------------------
__global__ __launch_bounds__(256, 2) void k_router(
    const float* __restrict__ x,
    const float* __restrict__ rw1, const float* __restrict__ rb1,
    const float* __restrict__ rw2, const float* __restrict__ rb2,
    const float* __restrict__ rw3, const float* __restrict__ rb3,
    float* __restrict__ probs_out, float* __restrict__ unc_out)
{
    __shared__ float XsT[32][68];    // [k][tok]
    __shared__ float WsT[32][132];   // [k][out 0..127]
    __shared__ float H1[64][132];    // [tok][128]
    __shared__ float H2[64][68];     // [tok][64]

    const int tid = threadIdx.x;
    const int tx = tid & 15, ty = tid >> 4;
    const long t0 = (long)blockIdx.x * TOK;

    float acc[4][8];
#pragma unroll
    for (int i = 0; i < 4; i++)
#pragma unroll
        for (int o = 0; o < 8; o++) acc[i][o] = 0.f;

    for (int kc = 0; kc < 16; kc++) {
        __syncthreads();
#pragma unroll
        for (int s = 0; s < 2; s++) {
            int id = tid + s * 256;
            int tok = id >> 3, kq = id & 7;
            float4 v = *(const float4*)&x[(t0 + tok) * 512 + kc * 32 + kq * 4];
            XsT[kq * 4 + 0][tok] = v.x; XsT[kq * 4 + 1][tok] = v.y;
            XsT[kq * 4 + 2][tok] = v.z; XsT[kq * 4 + 3][tok] = v.w;
        }
#pragma unroll
        for (int s = 0; s < 4; s++) {
            int id = tid + s * 256;
            int out = id >> 3, kq = id & 7;
            float4 v = *(const float4*)&rw1[(long)out * 512 + kc * 32 + kq * 4];
            WsT[kq * 4 + 0][out] = v.x; WsT[kq * 4 + 1][out] = v.y;
            WsT[kq * 4 + 2][out] = v.z; WsT[kq * 4 + 3][out] = v.w;
        }
        __syncthreads();
#pragma unroll
        for (int k = 0; k < 32; k++) {
            const float4 xv = *(const float4*)&XsT[k][ty * 4];
            const float4 wa = *(const float4*)&WsT[k][tx * 4];
            const float4 wb = *(const float4*)&WsT[k][64 + tx * 4];
            const float xs[4] = {xv.x, xv.y, xv.z, xv.w};
            const float ws[8] = {wa.x, wa.y, wa.z, wa.w, wb.x, wb.y, wb.z, wb.w};
#pragma unroll
            for (int i = 0; i < 4; i++)
#pragma unroll
                for (int o = 0; o < 8; o++)
                    acc[i][o] = fmaf(xs[i], ws[o], acc[i][o]);
        }
    }

#pragma unroll
    for (int o = 0; o < 8; o++) {
        const int col = (o < 4) ? (tx * 4 + o) : (64 + tx * 4 + (o - 4));
        float b = rb1[col];
#pragma unroll
        for (int i = 0; i < 4; i++) {
            float v = acc[i][o] + b;
            H1[ty * 4 + i][col] = v > 0.f ? v : 0.f;
        }
    }
    __syncthreads();

    float a2[4][4];
#pragma unroll
    for (int i = 0; i < 4; i++)
#pragma unroll
        for (int o = 0; o < 4; o++) a2[i][o] = 0.f;

    for (int k4 = 0; k4 < 32; k4++) {
        float4 hv[4], wv[4];
#pragma unroll
        for (int i = 0; i < 4; i++) hv[i] = *(const float4*)&H1[ty * 4 + i][k4 * 4];
#pragma unroll
        for (int o = 0; o < 4; o++) wv[o] = *(const float4*)&rw2[(tx * 4 + o) * 128 + k4 * 4];
#pragma unroll
        for (int i = 0; i < 4; i++)
#pragma unroll
            for (int o = 0; o < 4; o++)
                a2[i][o] += hv[i].x * wv[o].x + hv[i].y * wv[o].y +
                            hv[i].z * wv[o].z + hv[i].w * wv[o].w;
    }
#pragma unroll
    for (int o = 0; o < 4; o++) {
        float b = rb2[tx * 4 + o];
#pragma unroll
        for (int i = 0; i < 4; i++) {
            float v = a2[i][o] + b;
            H2[ty * 4 + i][tx * 4 + o] = v > 0.f ? v : 0.f;
        }
    }
    __syncthreads();

    if (tid < 64) {
        int tok = tid;
        float lg[4];
#pragma unroll
        for (int r = 0; r < 4; r++) {
            float s = rb3[r];
            for (int k4 = 0; k4 < 16; k4++) {
                float4 h = *(const float4*)&H2[tok][k4 * 4];
                float4 w = *(const float4*)&rw3[r * 64 + k4 * 4];
                s += h.x * w.x + h.y * w.y + h.z * w.z + h.w * w.w;
            }
            lg[r] = s;
        }
        float m = fmaxf(fmaxf(lg[0], lg[1]), fmaxf(lg[2], lg[3]));
        float e0 = __expf(lg[0] - m), e1 = __expf(lg[1] - m);
        float e2 = __expf(lg[2] - m), e3 = __expf(lg[3] - m);
        float inv = __builtin_amdgcn_rcpf(e0 + e1 + e2 + e3);
        float p0 = e0 * inv, p1 = e1 * inv, p2 = e2 * inv, p3 = e3 * inv;
        *(float4*)&probs_out[(t0 + tok) * 4] = make_float4(p0, p1, p2, p3);
        float mean = 0.25f * (p0 + p1 + p2 + p3);
        float d0 = p0 - mean, d1 = p1 - mean, d2 = p2 - mean, d3 = p3 - mean;
        unc_out[t0 + tok] = sqrtf((d0 * d0 + d1 * d1 + d2 * d2 + d3 * d3) * (1.f / 3.f));
    }
}

// ---------------------------------------------------------------------------
// Kernel 2 (512 threads): blocks 0..3 GRU — 8 batches per block, one wave
// each. 8 waves / 4 SIMDs = 2 GRU waves per SIMD, so each wave has a
// co-issue partner filling its issue/fetch bubbles (R12/R14 evidence: step
// time tracks instr count at ~4.8 cyc/instr = sole-wave issue starvation).
// Per-wave GRU code is byte-identical to R14 (bit-identical output).
// Blocks 4..1027: experts — work guarded by tid<256 (wave-uniform), barriers
// executed by all 512 threads (identical barrier sequence, no divergence).
// ---------------------------------------------------------------------------
__global__ __launch_bounds__(512, 2) void k_experts_gru(
    const float* __restrict__ x,
    const float* __restrict__ ew1, const float* __restrict__ eb1,
    const float* __restrict__ ew2, const float* __restrict__ eb2,
    const float* __restrict__ probs, float* __restrict__ weighted_out,
    const float* __restrict__ gwih, const float* __restrict__ gwhh,
    const float* __restrict__ gbih, const float* __restrict__ gbhh,
    float* __restrict__ trans_out)
{
    __shared__ float XsT[32][68];
    __shared__ float WsT[32][132];
    __shared__ float E1[64][132];
    __shared__ float pS[64][4];

    if (blockIdx.x < 4) {
        // ------------------------- GRU path -------------------------
        // wave w = tid>>6 handles batch b = blockIdx*8 + w. Lane l = tid&63:
        // j = l&31, half = l>>5. Math identical to R14.
        const int b = blockIdx.x * 8 + (threadIdx.x >> 6);
        const int l = threadIdx.x & 63;
        const int j = l & 31, half = l >> 5;
        const int kbase = half * 16;

        // packed W_hh for this lane's K-half: wpk[g][q] = {w[2q], w[2q+1]}
        v2f wpk[3][8];
#pragma unroll
        for (int g = 0; g < 3; g++) {
            const float* wp = gwhh + (j + 32 * g) * 32 + kbase;
#pragma unroll
            for (int q = 0; q < 8; q++) {
                v2f w; w.x = wp[2 * q]; w.y = wp[2 * q + 1];
                wpk[g][q] = w;
            }
        }
        float wih[3][4];
#pragma unroll
        for (int g = 0; g < 3; g++) {
            float4 w = *(const float4*)&gwih[(j + 32 * g) * 4];
            wih[g][0] = w.x; wih[g][1] = w.y; wih[g][2] = w.z; wih[g][3] = w.w;
        }
        const float bR = gbih[j] + gbhh[j];
        const float bZ = gbih[j + 32] + gbhh[j + 32];
        const float bIN = gbih[j + 64], bHN = gbhh[j + 64];

        const float* pb = probs + (long)b * 2048 * 4;
        v2f hpk[8];
#pragma unroll
        for (int q = 0; q < 8; q++) { hpk[q].x = 0.f; hpk[q].y = 0.f; }
        float hj = 0.f;
        float* tr = trans_out + (long)b * 2048 * 32 + j;

        // 8-deep circular prefetch, fully unrolled (static indices).
        float4 pbuf[8];
#pragma unroll
        for (int i = 0; i < 8; i++) pbuf[i] = *(const float4*)(pb + i * 4);

        for (int tg = 0; tg < 2048; tg += 8) {
            float hh[8];   // batched trans values (static indices -> VGPRs)
#pragma unroll
            for (int s = 0; s < 8; s++) {
                const float4 p0 = pbuf[s];
                int tf = tg + 8 + s;
                if (tf > 2047) tf = 2047;
                pbuf[s] = *(const float4*)(pb + tf * 4);   // in flight 8 steps

                // packed partial matvec (24 pk_fma == 48 scalar fma chains)
                v2f aR; aR.x = 0.f; aR.y = 0.f;
                v2f aZ = aR, aN = aR;
#pragma unroll
                for (int q = 0; q < 8; q++) {
                    aR = __builtin_elementwise_fma(wpk[0][q], hpk[q], aR);
                    aZ = __builtin_elementwise_fma(wpk[1][q], hpk[q], aZ);
                    aN = __builtin_elementwise_fma(wpk[2][q], hpk[q], aN);
                }
                float sR = xhalf_sum(aR.x + aR.y);
                float sZ = xhalf_sum(aZ.x + aZ.y);
                float sN = xhalf_sum(aN.x + aN.y);

                // input-gate dots (independent of h -> overlap swap latency)
                float giR = fmaf(wih[0][3], p0.w, fmaf(wih[0][2], p0.z,
                            fmaf(wih[0][1], p0.y, fmaf(wih[0][0], p0.x, bR))));
                float giZ = fmaf(wih[1][3], p0.w, fmaf(wih[1][2], p0.z,
                            fmaf(wih[1][1], p0.y, fmaf(wih[1][0], p0.x, bZ))));
                float giN = fmaf(wih[2][3], p0.w, fmaf(wih[2][2], p0.z,
                            fmaf(wih[2][1], p0.y, fmaf(wih[2][0], p0.x, bIN))));

                float r = __builtin_amdgcn_rcpf(1.f + __expf(-(giR + sR)));
                float z = __builtin_amdgcn_rcpf(1.f + __expf(-(giZ + sZ)));
                float nx = giN + r * (sN + bHN);
                float n = fmaf(2.f, __builtin_amdgcn_rcpf(1.f + __expf(-2.f * nx)), -1.f);
                hj = fmaf(z, hj - n, n);              // (1-z)*n + z*h

                hh[s] = hj;                            // store deferred

                // broadcast rebuild: 16 independent register-pulls (bpermute)
#pragma unroll
                for (int q = 0; q < 8; q++) {
                    hpk[q].x = __shfl(hj, kbase + 2 * q);
                    hpk[q].y = __shfl(hj, kbase + 2 * q + 1);
                }
            }
            // batched trans stores (group tail; lanes l and l^32 write the
            // same value to the same address, benign)
#pragma unroll
            for (int s = 0; s < 8; s++)
                tr[(tg + s) * 32] = hh[s];
        }
        return;
    }

    // ------------------------- experts path -------------------------
    // 512 threads traverse identical barriers; work done by tid<256 only.
    const int tid = threadIdx.x;
    const bool act = (tid < 256);
    const int tx = tid & 15, ty = (tid >> 4) & 15;
    const long t0 = (long)(blockIdx.x - 4) * TOK;

    if (tid < 64) *(float4*)&pS[tid][0] = *(const float4*)&probs[(t0 + tid) * 4];

    float wacc[4][8];
#pragma unroll
    for (int i = 0; i < 4; i++)
#pragma unroll
        for (int o = 0; o < 8; o++) wacc[i][o] = 0.f;

    for (int g = 0; g < 2; g++) {   // regime pairs {0,1}, {2,3}
        float acc[4][8];
#pragma unroll
        for (int i = 0; i < 4; i++)
#pragma unroll
            for (int o = 0; o < 8; o++) acc[i][o] = 0.f;

        for (int kc = 0; kc < 16; kc++) {
            __syncthreads();
            if (act) {
#pragma unroll
                for (int s = 0; s < 2; s++) {
                    int id = tid + s * 256;
                    int tok = id >> 3, kq = id & 7;
                    float4 v = *(const float4*)&x[(t0 + tok) * 512 + kc * 32 + kq * 4];
                    XsT[kq * 4 + 0][tok] = v.x; XsT[kq * 4 + 1][tok] = v.y;
                    XsT[kq * 4 + 2][tok] = v.z; XsT[kq * 4 + 3][tok] = v.w;
                }
#pragma unroll
                for (int s = 0; s < 4; s++) {
                    int id = tid + s * 256;
                    int out = id >> 3, kq = id & 7;
                    float4 v = *(const float4*)&ew1[(long)(g * 128 + out) * 512 + kc * 32 + kq * 4];
                    WsT[kq * 4 + 0][out] = v.x; WsT[kq * 4 + 1][out] = v.y;
                    WsT[kq * 4 + 2][out] = v.z; WsT[kq * 4 + 3][out] = v.w;
                }
            }
            __syncthreads();
            if (act) {
#pragma unroll
                for (int k = 0; k < 32; k++) {
                    const float4 xv = *(const float4*)&XsT[k][ty * 4];
                    const float4 wa = *(const float4*)&WsT[k][tx * 4];
                    const float4 wb = *(const float4*)&WsT[k][64 + tx * 4];
                    const float xs[4] = {xv.x, xv.y, xv.z, xv.w};
                    const float ws[8] = {wa.x, wa.y, wa.z, wa.w, wb.x, wb.y, wb.z, wb.w};
#pragma unroll
                    for (int i = 0; i < 4; i++)
#pragma unroll
                        for (int o = 0; o < 8; o++)
                            acc[i][o] = fmaf(xs[i], ws[o], acc[i][o]);
                }
            }
        }
        __syncthreads();
        if (act) {
#pragma unroll
            for (int o = 0; o < 8; o++) {
                const int col = (o < 4) ? (tx * 4 + o) : (64 + tx * 4 + (o - 4));
                float b = eb1[g * 128 + col];
#pragma unroll
                for (int i = 0; i < 4; i++) {
                    float v = acc[i][o] + b;
                    E1[ty * 4 + i][col] = v > 0.f ? v : 0.f;
                }
            }
        }
        __syncthreads();

        if (act) {
            const int rl = tx >> 3;
            const int fb = (tx & 7) * 8;
            const int rg = g * 2 + rl;

            float a2[4][8];
#pragma unroll
            for (int i = 0; i < 4; i++)
#pragma unroll
                for (int o = 0; o < 8; o++) a2[i][o] = 0.f;

            for (int k4 = 0; k4 < 16; k4++) {
                float4 hv[4];
#pragma unroll
                for (int i = 0; i < 4; i++)
                    hv[i] = *(const float4*)&E1[ty * 4 + i][rl * 64 + k4 * 4];
#pragma unroll
                for (int o = 0; o < 8; o++) {
                    float4 wv = *(const float4*)&ew2[(long)(rg * 64 + fb + o) * 64 + k4 * 4];
#pragma unroll
                    for (int i = 0; i < 4; i++)
                        a2[i][o] += hv[i].x * wv.x + hv[i].y * wv.y +
                                    hv[i].z * wv.z + hv[i].w * wv.w;
                }
            }
            float pr[4];
#pragma unroll
            for (int i = 0; i < 4; i++) pr[i] = pS[ty * 4 + i][rg];
#pragma unroll
            for (int o = 0; o < 8; o++) {
                float b = eb2[rg * 64 + fb + o];
#pragma unroll
                for (int i = 0; i < 4; i++) {
                    float v = a2[i][o] + b;
                    v = v > 0.f ? v : 0.f;
                    wacc[i][o] = fmaf(pr[i], v, wacc[i][o]);
                }
            }
        }
        __syncthreads();  // protect E1/staging before next pass overwrites
    }

    if (act) {
#pragma unroll
        for (int i = 0; i < 4; i++)
#pragma unroll
            for (int o = 0; o < 8; o++)
                wacc[i][o] += __shfl_xor(wacc[i][o], 8);

        if ((tx & 8) == 0) {
#pragma unroll
            for (int i = 0; i < 4; i++) {
                float4 v0 = make_float4(wacc[i][0], wacc[i][1], wacc[i][2], wacc[i][3]);
                float4 v1 = make_float4(wacc[i][4], wacc[i][5], wacc[i][6], wacc[i][7]);
                long base = (t0 + ty * 4 + i) * 64 + (tx & 7) * 8;
                *(float4*)&weighted_out[base] = v0;
                *(float4*)&weighted_out[base + 4] = v1;
            }
        }
    }
}

extern "C" void kernel_launch(void* const* d_in, const int* in_sizes, int n_in,
                              void* d_out, int out_size, void* d_ws, size_t ws_size,
                              hipStream_t stream) {
    const float* x    = (const float*)d_in[0];
    const float* rw1  = (const float*)d_in[1];
    const float* rb1  = (const float*)d_in[2];
    const float* rw2  = (const float*)d_in[3];
    const float* rb2  = (const float*)d_in[4];
    const float* rw3  = (const float*)d_in[5];
    const float* rb3  = (const float*)d_in[6];
    const float* ew1  = (const float*)d_in[7];
    const float* eb1  = (const float*)d_in[8];
    const float* ew2  = (const float*)d_in[9];
    const float* eb2  = (const float*)d_in[10];
    const float* gwih = (const float*)d_in[11];
    const float* gwhh = (const float*)d_in[12];
    const float* gbih = (const float*)d_in[13];
    const float* gbhh = (const float*)d_in[14];

    float* out        = (float*)d_out;
    float* probs_o    = out;                         // 32*2048*4
    float* weighted_o = out + 262144;                // 32*2048*64
    float* trans_o    = out + 262144 + 4194304;      // 32*2048*32
    float* unc_o      = trans_o + 2097152;           // 32*2048

    hipLaunchKernelGGL(k_router, dim3(NTILE), dim3(256), 0, stream,
                       x, rw1, rb1, rw2, rb2, rw3, rb3, probs_o, unc_o);
    hipLaunchKernelGGL(k_experts_gru, dim3(NTILE + 4), dim3(512), 0, stream,
                       x, ew1, eb1, ew2, eb2, probs_o, weighted_o,
                       gwih, gwhh, gbih, gbhh, trans_o);
}

// Round 16
// 732.337 us; speedup vs baseline: 1.3437x; 1.3437x over previous
//
#include <hip/hip_runtime.h>
#include <math.h>

// B=32, S=2048, D=512, R=4, H=32. Tokens = 65536. Tile = 64 tokens.
#define NTOK 65536
#define TOK 64
#define NTILE 1024

typedef float v2f __attribute__((ext_vector_type(2)));

// Cross-half sum via the gfx950 permlane32_swap BUILTIN (SSA-safe; never the
// inline-asm "+v","+v" form — R4: allocator coalesces identical tied operands
// -> self-swap). r0+r1 == x + shfl_xor(x,32) bit-exactly (fp add commutes).
__device__ __forceinline__ float xhalf_sum(float a) {
    unsigned ai = __builtin_bit_cast(unsigned, a);
    auto r = __builtin_amdgcn_permlane32_swap(ai, ai, false, false);
    return __builtin_bit_cast(float, (unsigned)r[0]) +
           __builtin_bit_cast(float, (unsigned)r[1]);
}

// ---------------------------------------------------------------------------
// Kernel 1: router (UNCHANGED from the passing R5/R10 kernel).
// ---------------------------------------------------------------------------
__global__ __launch_bounds__(256, 2) void k_router(
    const float* __restrict__ x,
    const float* __restrict__ rw1, const float* __restrict__ rb1,
    const float* __restrict__ rw2, const float* __restrict__ rb2,
    const float* __restrict__ rw3, const float* __restrict__ rb3,
    float* __restrict__ probs_out, float* __restrict__ unc_out)
{
    __shared__ float XsT[32][68];    // [k][tok]
    __shared__ float WsT[32][132];   // [k][out 0..127]
    __shared__ float H1[64][132];    // [tok][128]
    __shared__ float H2[64][68];     // [tok][64]

    const int tid = threadIdx.x;
    const int tx = tid & 15, ty = tid >> 4;
    const long t0 = (long)blockIdx.x * TOK;

    float acc[4][8];
#pragma unroll
    for (int i = 0; i < 4; i++)
#pragma unroll
        for (int o = 0; o < 8; o++) acc[i][o] = 0.f;

    for (int kc = 0; kc < 16; kc++) {
        __syncthreads();
#pragma unroll
        for (int s = 0; s < 2; s++) {
            int id = tid + s * 256;
            int tok = id >> 3, kq = id & 7;
            float4 v = *(const float4*)&x[(t0 + tok) * 512 + kc * 32 + kq * 4];
            XsT[kq * 4 + 0][tok] = v.x; XsT[kq * 4 + 1][tok] = v.y;
            XsT[kq * 4 + 2][tok] = v.z; XsT[kq * 4 + 3][tok] = v.w;
        }
#pragma unroll
        for (int s = 0; s < 4; s++) {
            int id = tid + s * 256;
            int out = id >> 3, kq = id & 7;
            float4 v = *(const float4*)&rw1[(long)out * 512 + kc * 32 + kq * 4];
            WsT[kq * 4 + 0][out] = v.x; WsT[kq * 4 + 1][out] = v.y;
            WsT[kq * 4 + 2][out] = v.z; WsT[kq * 4 + 3][out] = v.w;
        }
        __syncthreads();
#pragma unroll
        for (int k = 0; k < 32; k++) {
            const float4 xv = *(const float4*)&XsT[k][ty * 4];
            const float4 wa = *(const float4*)&WsT[k][tx * 4];
            const float4 wb = *(const float4*)&WsT[k][64 + tx * 4];
            const float xs[4] = {xv.x, xv.y, xv.z, xv.w};
            const float ws[8] = {wa.x, wa.y, wa.z, wa.w, wb.x, wb.y, wb.z, wb.w};
#pragma unroll
            for (int i = 0; i < 4; i++)
#pragma unroll
                for (int o = 0; o < 8; o++)
                    acc[i][o] = fmaf(xs[i], ws[o], acc[i][o]);
        }
    }

#pragma unroll
    for (int o = 0; o < 8; o++) {
        const int col = (o < 4) ? (tx * 4 + o) : (64 + tx * 4 + (o - 4));
        float b = rb1[col];
#pragma unroll
        for (int i = 0; i < 4; i++) {
            float v = acc[i][o] + b;
            H1[ty * 4 + i][col] = v > 0.f ? v : 0.f;
        }
    }
    __syncthreads();

    float a2[4][4];
#pragma unroll
    for (int i = 0; i < 4; i++)
#pragma unroll
        for (int o = 0; o < 4; o++) a2[i][o] = 0.f;

    for (int k4 = 0; k4 < 32; k4++) {
        float4 hv[4], wv[4];
#pragma unroll
        for (int i = 0; i < 4; i++) hv[i] = *(const float4*)&H1[ty * 4 + i][k4 * 4];
#pragma unroll
        for (int o = 0; o < 4; o++) wv[o] = *(const float4*)&rw2[(tx * 4 + o) * 128 + k4 * 4];
#pragma unroll
        for (int i = 0; i < 4; i++)
#pragma unroll
            for (int o = 0; o < 4; o++)
                a2[i][o] += hv[i].x * wv[o].x + hv[i].y * wv[o].y +
                            hv[i].z * wv[o].z + hv[i].w * wv[o].w;
    }
#pragma unroll
    for (int o = 0; o < 4; o++) {
        float b = rb2[tx * 4 + o];
#pragma unroll
        for (int i = 0; i < 4; i++) {
            float v = a2[i][o] + b;
            H2[ty * 4 + i][tx * 4 + o] = v > 0.f ? v : 0.f;
        }
    }
    __syncthreads();

    if (tid < 64) {
        int tok = tid;
        float lg[4];
#pragma unroll
        for (int r = 0; r < 4; r++) {
            float s = rb3[r];
            for (int k4 = 0; k4 < 16; k4++) {
                float4 h = *(const float4*)&H2[tok][k4 * 4];
                float4 w = *(const float4*)&rw3[r * 64 + k4 * 4];
                s += h.x * w.x + h.y * w.y + h.z * w.z + h.w * w.w;
            }
            lg[r] = s;
        }
        float m = fmaxf(fmaxf(lg[0], lg[1]), fmaxf(lg[2], lg[3]));
        float e0 = __expf(lg[0] - m), e1 = __expf(lg[1] - m);
        float e2 = __expf(lg[2] - m), e3 = __expf(lg[3] - m);
        float inv = __builtin_amdgcn_rcpf(e0 + e1 + e2 + e3);
        float p0 = e0 * inv, p1 = e1 * inv, p2 = e2 * inv, p3 = e3 * inv;
        *(float4*)&probs_out[(t0 + tok) * 4] = make_float4(p0, p1, p2, p3);
        float mean = 0.25f * (p0 + p1 + p2 + p3);
        float d0 = p0 - mean, d1 = p1 - mean, d2 = p2 - mean, d3 = p3 - mean;
        unc_out[t0 + tok] = sqrtf((d0 * d0 + d1 * d1 + d2 * d2 + d3 * d3) * (1.f / 3.f));
    }
}

// ---------------------------------------------------------------------------
// Kernel 2: blocks 0..31 GRU; blocks 32..1055 experts (UNCHANGED from R10).
//
// GRU = R12 (packed pk_fma dot, 16-shfl broadcast, 8-deep circular prefetch)
// with trans stores batched at the group tail (R14). Latency-bound at ~675
// cyc/step (R12/R14/R15 evidence); math bit-identical since R9.
// ---------------------------------------------------------------------------
__global__ __launch_bounds__(256, 2) void k_experts_gru(
    const float* __restrict__ x,
    const float* __restrict__ ew1, const float* __restrict__ eb1,
    const float* __restrict__ ew2, const float* __restrict__ eb2,
    const float* __restrict__ probs, float* __restrict__ weighted_out,
    const float* __restrict__ gwih, const float* __restrict__ gwhh,
    const float* __restrict__ gbih, const float* __restrict__ gbhh,
    float* __restrict__ trans_out)
{
    if (blockIdx.x < 32) {
        // ------------------------- GRU path -------------------------
        if (threadIdx.x >= 64) return;
        const int b = blockIdx.x;
        const int l = threadIdx.x;
        const int j = l & 31, half = l >> 5;
        const int kbase = half * 16;

        // packed W_hh for this lane's K-half: wpk[g][q] = {w[2q], w[2q+1]}
        v2f wpk[3][8];
#pragma unroll
        for (int g = 0; g < 3; g++) {
            const float* wp = gwhh + (j + 32 * g) * 32 + kbase;
#pragma unroll
            for (int q = 0; q < 8; q++) {
                v2f w; w.x = wp[2 * q]; w.y = wp[2 * q + 1];
                wpk[g][q] = w;
            }
        }
        float wih[3][4];
#pragma unroll
        for (int g = 0; g < 3; g++) {
            float4 w = *(const float4*)&gwih[(j + 32 * g) * 4];
            wih[g][0] = w.x; wih[g][1] = w.y; wih[g][2] = w.z; wih[g][3] = w.w;
        }
        const float bR = gbih[j] + gbhh[j];
        const float bZ = gbih[j + 32] + gbhh[j + 32];
        const float bIN = gbih[j + 64], bHN = gbhh[j + 64];

        const float* pb = probs + (long)b * 2048 * 4;
        v2f hpk[8];
#pragma unroll
        for (int q = 0; q < 8; q++) { hpk[q].x = 0.f; hpk[q].y = 0.f; }
        float hj = 0.f;
        float* tr = trans_out + (long)b * 2048 * 32 + j;

        // 8-deep circular prefetch, fully unrolled (static indices).
        float4 pbuf[8];
#pragma unroll
        for (int i = 0; i < 8; i++) pbuf[i] = *(const float4*)(pb + i * 4);

        for (int tg = 0; tg < 2048; tg += 8) {
            float hh[8];   // batched trans values (static indices -> VGPRs)
#pragma unroll
            for (int s = 0; s < 8; s++) {
                const float4 p0 = pbuf[s];
                int tf = tg + 8 + s;
                if (tf > 2047) tf = 2047;
                pbuf[s] = *(const float4*)(pb + tf * 4);   // in flight 8 steps

                // packed partial matvec (24 pk_fma == 48 scalar fma chains)
                v2f aR; aR.x = 0.f; aR.y = 0.f;
                v2f aZ = aR, aN = aR;
#pragma unroll
                for (int q = 0; q < 8; q++) {
                    aR = __builtin_elementwise_fma(wpk[0][q], hpk[q], aR);
                    aZ = __builtin_elementwise_fma(wpk[1][q], hpk[q], aZ);
                    aN = __builtin_elementwise_fma(wpk[2][q], hpk[q], aN);
                }
                float sR = xhalf_sum(aR.x + aR.y);
                float sZ = xhalf_sum(aZ.x + aZ.y);
                float sN = xhalf_sum(aN.x + aN.y);

                // input-gate dots (independent of h -> overlap swap latency)
                float giR = fmaf(wih[0][3], p0.w, fmaf(wih[0][2], p0.z,
                            fmaf(wih[0][1], p0.y, fmaf(wih[0][0], p0.x, bR))));
                float giZ = fmaf(wih[1][3], p0.w, fmaf(wih[1][2], p0.z,
                            fmaf(wih[1][1], p0.y, fmaf(wih[1][0], p0.x, bZ))));
                float giN = fmaf(wih[2][3], p0.w, fmaf(wih[2][2], p0.z,
                            fmaf(wih[2][1], p0.y, fmaf(wih[2][0], p0.x, bIN))));

                float r = __builtin_amdgcn_rcpf(1.f + __expf(-(giR + sR)));
                float z = __builtin_amdgcn_rcpf(1.f + __expf(-(giZ + sZ)));
                float nx = giN + r * (sN + bHN);
                float n = fmaf(2.f, __builtin_amdgcn_rcpf(1.f + __expf(-2.f * nx)), -1.f);
                hj = fmaf(z, hj - n, n);              // (1-z)*n + z*h

                hh[s] = hj;                            // store deferred

                // broadcast rebuild: 16 independent register-pulls (bpermute)
#pragma unroll
                for (int q = 0; q < 8; q++) {
                    hpk[q].x = __shfl(hj, kbase + 2 * q);
                    hpk[q].y = __shfl(hj, kbase + 2 * q + 1);
                }
            }
            // batched trans stores (group tail; lanes l and l^32 write the
            // same value to the same address, benign)
#pragma unroll
            for (int s = 0; s < 8; s++)
                tr[(tg + s) * 32] = hh[s];
        }
        return;
    }

    // ------------------------- experts path (R10, unchanged) -------------------------
    __shared__ float XsT[32][68];
    __shared__ float WsT[32][132];
    __shared__ float E1[64][132];
    __shared__ float pS[64][4];

    const int tid = threadIdx.x;
    const int tx = tid & 15, ty = tid >> 4;
    const long t0 = (long)(blockIdx.x - 32) * TOK;

    if (tid < 64) *(float4*)&pS[tid][0] = *(const float4*)&probs[(t0 + tid) * 4];

    float wacc[4][8];
#pragma unroll
    for (int i = 0; i < 4; i++)
#pragma unroll
        for (int o = 0; o < 8; o++) wacc[i][o] = 0.f;

    for (int g = 0; g < 2; g++) {   // regime pairs {0,1}, {2,3}
        float acc[4][8];
#pragma unroll
        for (int i = 0; i < 4; i++)
#pragma unroll
            for (int o = 0; o < 8; o++) acc[i][o] = 0.f;

        for (int kc = 0; kc < 16; kc++) {
            __syncthreads();
#pragma unroll
            for (int s = 0; s < 2; s++) {
                int id = tid + s * 256;
                int tok = id >> 3, kq = id & 7;
                float4 v = *(const float4*)&x[(t0 + tok) * 512 + kc * 32 + kq * 4];
                XsT[kq * 4 + 0][tok] = v.x; XsT[kq * 4 + 1][tok] = v.y;
                XsT[kq * 4 + 2][tok] = v.z; XsT[kq * 4 + 3][tok] = v.w;
            }
#pragma unroll
            for (int s = 0; s < 4; s++) {
                int id = tid + s * 256;
                int out = id >> 3, kq = id & 7;
                float4 v = *(const float4*)&ew1[(long)(g * 128 + out) * 512 + kc * 32 + kq * 4];
                WsT[kq * 4 + 0][out] = v.x; WsT[kq * 4 + 1][out] = v.y;
                WsT[kq * 4 + 2][out] = v.z; WsT[kq * 4 + 3][out] = v.w;
            }
            __syncthreads();
#pragma unroll
            for (int k = 0; k < 32; k++) {
                const float4 xv = *(const float4*)&XsT[k][ty * 4];
                const float4 wa = *(const float4*)&WsT[k][tx * 4];
                const float4 wb = *(const float4*)&WsT[k][64 + tx * 4];
                const float xs[4] = {xv.x, xv.y, xv.z, xv.w};
                const float ws[8] = {wa.x, wa.y, wa.z, wa.w, wb.x, wb.y, wb.z, wb.w};
#pragma unroll
                for (int i = 0; i < 4; i++)
#pragma unroll
                    for (int o = 0; o < 8; o++)
                        acc[i][o] = fmaf(xs[i], ws[o], acc[i][o]);
            }
        }
        __syncthreads();
#pragma unroll
        for (int o = 0; o < 8; o++) {
            const int col = (o < 4) ? (tx * 4 + o) : (64 + tx * 4 + (o - 4));
            float b = eb1[g * 128 + col];
#pragma unroll
            for (int i = 0; i < 4; i++) {
                float v = acc[i][o] + b;
                E1[ty * 4 + i][col] = v > 0.f ? v : 0.f;
            }
        }
        __syncthreads();

        const int rl = tx >> 3;
        const int fb = (tx & 7) * 8;
        const int rg = g * 2 + rl;

        float a2[4][8];
#pragma unroll
        for (int i = 0; i < 4; i++)
#pragma unroll
            for (int o = 0; o < 8; o++) a2[i][o] = 0.f;

        for (int k4 = 0; k4 < 16; k4++) {
            float4 hv[4];
#pragma unroll
            for (int i = 0; i < 4; i++)
                hv[i] = *(const float4*)&E1[ty * 4 + i][rl * 64 + k4 * 4];
#pragma unroll
            for (int o = 0; o < 8; o++) {
                float4 wv = *(const float4*)&ew2[(long)(rg * 64 + fb + o) * 64 + k4 * 4];
#pragma unroll
                for (int i = 0; i < 4; i++)
                    a2[i][o] += hv[i].x * wv.x + hv[i].y * wv.y +
                                hv[i].z * wv.z + hv[i].w * wv.w;
            }
        }
        float pr[4];
#pragma unroll
        for (int i = 0; i < 4; i++) pr[i] = pS[ty * 4 + i][rg];
#pragma unroll
        for (int o = 0; o < 8; o++) {
            float b = eb2[rg * 64 + fb + o];
#pragma unroll
            for (int i = 0; i < 4; i++) {
                float v = a2[i][o] + b;
                v = v > 0.f ? v : 0.f;
                wacc[i][o] = fmaf(pr[i], v, wacc[i][o]);
            }
        }
        __syncthreads();
    }

#pragma unroll
    for (int i = 0; i < 4; i++)
#pragma unroll
        for (int o = 0; o < 8; o++)
            wacc[i][o] += __shfl_xor(wacc[i][o], 8);

    if ((tx & 8) == 0) {
#pragma unroll
        for (int i = 0; i < 4; i++) {
            float4 v0 = make_float4(wacc[i][0], wacc[i][1], wacc[i][2], wacc[i][3]);
            float4 v1 = make_float4(wacc[i][4], wacc[i][5], wacc[i][6], wacc[i][7]);
            long base = (t0 + ty * 4 + i) * 64 + (tx & 7) * 8;
            *(float4*)&weighted_out[base] = v0;
            *(float4*)&weighted_out[base + 4] = v1;
        }
    }
}

extern "C" void kernel_launch(void* const* d_in, const int* in_sizes, int n_in,
                              void* d_out, int out_size, void* d_ws, size_t ws_size,
                              hipStream_t stream) {
    const float* x    = (const float*)d_in[0];
    const float* rw1  = (const float*)d_in[1];
    const float* rb1  = (const float*)d_in[2];
    const float* rw2  = (const float*)d_in[3];
    const float* rb2  = (const float*)d_in[4];
    const float* rw3  = (const float*)d_in[5];
    const float* rb3  = (const float*)d_in[6];
    const float* ew1  = (const float*)d_in[7];
    const float* eb1  = (const float*)d_in[8];
    const float* ew2  = (const float*)d_in[9];
    const float* eb2  = (const float*)d_in[10];
    const float* gwih = (const float*)d_in[11];
    const float* gwhh = (const float*)d_in[12];
    const float* gbih = (const float*)d_in[13];
    const float* gbhh = (const float*)d_in[14];

    float* out        = (float*)d_out;
    float* probs_o    = out;                         // 32*2048*4
    float* weighted_o = out + 262144;                // 32*2048*64
    float* trans_o    = out + 262144 + 4194304;      // 32*2048*32
    float* unc_o      = trans_o + 2097152;           // 32*2048

    hipLaunchKernelGGL(k_router, dim3(NTILE), dim3(256), 0, stream,
                       x, rw1, rb1, rw2, rb2, rw3, rb3, probs_o, unc_o);
    hipLaunchKernelGGL(k_experts_gru, dim3(NTILE + 32), dim3(256), 0, stream,
                       x, ew1, eb1, ew2, eb2, probs_o, weighted_o,
                       gwih, gwhh, gbih, gbhh, trans_o);
}